// Round 1
// baseline (129.514 us; speedup 1.0000x reference)
//
#include <hip/hip_runtime.h>
#include <hip/hip_bf16.h>

// Problem: B=16, C=4, H=512, W=512 ; rows = B*C = 64 ; row length = H*W = 262144
// k = int(0.1 * 262144) = 26214 ; answer = sum(topk over all rows) / (64*26214)

#define ROWS 64
#define ROW_N4 65536            // float4 per row (262144 floats)
#define K_SEL 26214u
#define BLOCKS_PER_ROW 32
#define CHUNK4 2048             // float4 per block
#define THREADS 256
#define BINS 2048

__device__ __forceinline__ unsigned loss_bits(float x, float y, float* val) {
    // numerically stable BCE-with-logits: max(x,0) - x*y + log1p(exp(-|x|))
    float l = fmaxf(x, 0.0f) - x * y + log1pf(__expf(-fabsf(x)));
    *val = l;
    return __float_as_uint(l);   // l > 0 always -> bits order like unsigned
}

// ---------------- Pass 1: per-row histogram of top 11 bits ----------------
__global__ __launch_bounds__(THREADS)
void k_hist1(const float4* __restrict__ lg, const float4* __restrict__ tg,
             unsigned* __restrict__ hist1) {
    __shared__ unsigned h[BINS];
    int t = threadIdx.x;
    for (int i = t; i < BINS; i += THREADS) h[i] = 0;
    __syncthreads();

    int row = blockIdx.x >> 5;          // / BLOCKS_PER_ROW
    int chunk = blockIdx.x & 31;
    int base = row * ROW_N4 + chunk * CHUNK4;

#pragma unroll
    for (int j = 0; j < 8; ++j) {
        int idx = base + j * THREADS + t;
        float4 x = lg[idx];
        float4 y = tg[idx];
        float v;
        atomicAdd(&h[loss_bits(x.x, y.x, &v) >> 21], 1u);
        atomicAdd(&h[loss_bits(x.y, y.y, &v) >> 21], 1u);
        atomicAdd(&h[loss_bits(x.z, y.z, &v) >> 21], 1u);
        atomicAdd(&h[loss_bits(x.w, y.w, &v) >> 21], 1u);
    }
    __syncthreads();
    unsigned* gh = hist1 + row * BINS;
    for (int i = t; i < BINS; i += THREADS) {
        unsigned c = h[i];
        if (c) atomicAdd(&gh[i], c);
    }
}

// ---------------- Scan 1: find candidate bin b1 and rem1 per row ----------------
__global__ __launch_bounds__(THREADS)
void k_scan1(const unsigned* __restrict__ hist1, uint2* __restrict__ state1) {
    int row = blockIdx.x;
    int t = threadIdx.x;
    __shared__ unsigned h[BINS];
    __shared__ unsigned csum[THREADS];
    for (int i = t; i < BINS; i += THREADS) h[i] = hist1[row * BINS + i];
    __syncthreads();

    unsigned s = 0;
#pragma unroll
    for (int j = 0; j < 8; ++j) s += h[t * 8 + j];
    csum[t] = s;
    __syncthreads();
    // suffix scan: csum[t] = sum over chunks [t..255]
    for (int off = 1; off < THREADS; off <<= 1) {
        unsigned add = (t + off < THREADS) ? csum[t + off] : 0;
        __syncthreads();
        csum[t] += add;
        __syncthreads();
    }
    unsigned suffIncl = csum[t];
    unsigned suffExcl = (t + 1 < THREADS) ? csum[t + 1] : 0;
    if (suffExcl < K_SEL && suffIncl >= K_SEL) {
        unsigned cum = suffExcl;
        for (int j = 7; j >= 0; --j) {
            unsigned c = h[t * 8 + j];
            if (cum + c >= K_SEL) {
                state1[row] = make_uint2((unsigned)(t * 8 + j), K_SEL - cum);
                break;
            }
            cum += c;
        }
    }
}

// ---------------- Pass 2: exact sum above b1, level-2 hist (counts+sums) in b1 ----------------
__global__ __launch_bounds__(THREADS)
void k_pass2(const float4* __restrict__ lg, const float4* __restrict__ tg,
             const uint2* __restrict__ state1,
             unsigned* __restrict__ hist2c, float* __restrict__ hist2s,
             double* __restrict__ rowsum) {
    __shared__ unsigned hc[BINS];
    __shared__ float hs[BINS];
    __shared__ float red[THREADS];
    int t = threadIdx.x;
    for (int i = t; i < BINS; i += THREADS) { hc[i] = 0; hs[i] = 0.0f; }
    __syncthreads();

    int row = blockIdx.x >> 5;
    int chunk = blockIdx.x & 31;
    unsigned b1 = state1[row].x;
    int base = row * ROW_N4 + chunk * CHUNK4;

    float localsum = 0.0f;
#pragma unroll
    for (int j = 0; j < 8; ++j) {
        int idx = base + j * THREADS + t;
        float4 x = lg[idx];
        float4 y = tg[idx];
        float v; unsigned bits, t11;
#define PROC(CX, CY)                                            \
        bits = loss_bits(CX, CY, &v);                           \
        t11 = bits >> 21;                                       \
        if (t11 > b1) localsum += v;                            \
        else if (t11 == b1) {                                   \
            unsigned mid = (bits >> 10) & 0x7FFu;               \
            atomicAdd(&hc[mid], 1u);                            \
            atomicAdd(&hs[mid], v);                             \
        }
        PROC(x.x, y.x) PROC(x.y, y.y) PROC(x.z, y.z) PROC(x.w, y.w)
#undef PROC
    }
    __syncthreads();
    unsigned* ghc = hist2c + row * BINS;
    float* ghs = hist2s + row * BINS;
    for (int i = t; i < BINS; i += THREADS) {
        unsigned c = hc[i];
        if (c) { atomicAdd(&ghc[i], c); atomicAdd(&ghs[i], hs[i]); }
    }
    // block-reduce localsum
    red[t] = localsum;
    __syncthreads();
    for (int off = THREADS / 2; off > 0; off >>= 1) {
        if (t < off) red[t] += red[t + off];
        __syncthreads();
    }
    if (t == 0) atomicAdd(&rowsum[row], (double)red[0]);
}

// ---------------- Scan 2: finish per-row topk sum, accumulate global ----------------
__global__ __launch_bounds__(THREADS)
void k_scan2(const unsigned* __restrict__ hist2c, const float* __restrict__ hist2s,
             const uint2* __restrict__ state1, const double* __restrict__ rowsum,
             double* __restrict__ acc) {
    int row = blockIdx.x;
    int t = threadIdx.x;
    __shared__ unsigned hc[BINS];
    __shared__ float hs[BINS];
    __shared__ unsigned csum[THREADS];
    __shared__ float fred[THREADS];
    __shared__ int sh_b2;
    __shared__ unsigned sh_take;
    for (int i = t; i < BINS; i += THREADS) {
        hc[i] = hist2c[row * BINS + i];
        hs[i] = hist2s[row * BINS + i];
    }
    __syncthreads();

    unsigned b1 = state1[row].x;
    unsigned rem1 = state1[row].y;

    unsigned s = 0;
#pragma unroll
    for (int j = 0; j < 8; ++j) s += hc[t * 8 + j];
    csum[t] = s;
    __syncthreads();
    for (int off = 1; off < THREADS; off <<= 1) {
        unsigned add = (t + off < THREADS) ? csum[t + off] : 0;
        __syncthreads();
        csum[t] += add;
        __syncthreads();
    }
    unsigned suffIncl = csum[t];
    unsigned suffExcl = (t + 1 < THREADS) ? csum[t + 1] : 0;
    if (suffExcl < rem1 && suffIncl >= rem1) {
        unsigned cum = suffExcl;
        for (int j = 7; j >= 0; --j) {
            unsigned c = hc[t * 8 + j];
            if (cum + c >= rem1) {
                sh_b2 = t * 8 + j;
                sh_take = rem1 - cum;
                break;
            }
            cum += c;
        }
    }
    __syncthreads();
    int b2 = sh_b2;
    unsigned take = sh_take;

    // exact sum of full bins above b2
    float fs = 0.0f;
#pragma unroll
    for (int j = 0; j < 8; ++j) {
        int bin = t * 8 + j;
        if (bin > b2) fs += hs[bin];
    }
    fred[t] = fs;
    __syncthreads();
    for (int off = THREADS / 2; off > 0; off >>= 1) {
        if (t < off) fred[t] += fred[t + off];
        __syncthreads();
    }
    if (t == 0) {
        // midpoint of the partial (22-bit-resolved) bin: relative width ~2^-13
        float vmid = __uint_as_float((b1 << 21) | ((unsigned)b2 << 10) | 0x200u);
        double total = rowsum[row] + (double)fred[0] + (double)take * (double)vmid;
        atomicAdd(acc, total);
    }
}

__global__ void k_final(const double* __restrict__ acc, float* __restrict__ out) {
    out[0] = (float)(acc[0] / (double)(ROWS * (double)K_SEL));
}

extern "C" void kernel_launch(void* const* d_in, const int* in_sizes, int n_in,
                              void* d_out, int out_size, void* d_ws, size_t ws_size,
                              hipStream_t stream) {
    const float4* lg = (const float4*)d_in[0];
    const float4* tg = (const float4*)d_in[1];
    float* out = (float*)d_out;

    // workspace layout
    char* ws = (char*)d_ws;
    unsigned* hist1  = (unsigned*)(ws);                 // 64*2048*4 = 524288
    unsigned* hist2c = (unsigned*)(ws + 524288);        // 524288
    float*    hist2s = (float*)   (ws + 1048576);       // 524288
    double*   rowsum = (double*)  (ws + 1572864);       // 512
    uint2*    state1 = (uint2*)   (ws + 1573376);       // 512
    double*   acc    = (double*)  (ws + 1573888);       // 8
    size_t needed = 1573896;
    (void)in_sizes; (void)n_in; (void)out_size; (void)ws_size;

    hipMemsetAsync(d_ws, 0, needed, stream);

    dim3 big(ROWS * BLOCKS_PER_ROW);   // 2048 blocks
    k_hist1<<<big, THREADS, 0, stream>>>(lg, tg, hist1);
    k_scan1<<<ROWS, THREADS, 0, stream>>>(hist1, state1);
    k_pass2<<<big, THREADS, 0, stream>>>(lg, tg, state1, hist2c, hist2s, rowsum);
    k_scan2<<<ROWS, THREADS, 0, stream>>>(hist2c, hist2s, state1, rowsum, acc);
    k_final<<<1, 1, 0, stream>>>(acc, out);
}

// Round 3
// 62.371 us; speedup vs baseline: 2.0765x; 2.0765x over previous
//
#include <hip/hip_runtime.h>

// B=16, C=4, H=512, W=512 ; rows=64 ; row length=262144 ; k=26214
// answer = sum(topk loss per row) / (64*26214)

#define ROWS 64
#define ROW_N4 65536            // float4 per row
#define K_SEL 26214u
#define CHUNK4 2048             // float4 per block
#define THREADS 256
#define BINS1 2048              // top-11 bits of u16
#define BINS2 32                // low-5 bits of u16

// fast BCE-with-logits: max(x,0) - x*y + log1p(exp(-|x|))
// log1p(e^-a) = ln2 * log2(1 + 2^(-a*log2e)) -> v_exp_f32 + v_log_f32
__device__ __forceinline__ float loss_fast(float x, float y) {
    float a = fabsf(x);
    float t = __builtin_amdgcn_exp2f(a * -1.44269504088896f);   // 2^(-a*log2e) = e^-a
    float sp = 0.69314718055995f * __builtin_amdgcn_logf(1.0f + t); // ln2*log2(1+t)
    return fmaxf(x, 0.0f) - x * y + sp;
}
// round float bits to nearest 16-bit prefix (monotone, unbiased)
__device__ __forceinline__ unsigned to_u16(float l) {
    return (__float_as_uint(l) + 0x8000u) >> 16;
}
__device__ __forceinline__ float u16_val(unsigned u) {
    return __uint_as_float(u << 16);
}

// ---------- Pass 1: compute loss, (optionally store u16), 2048-bin histogram ----------
template<bool STORE>
__global__ __launch_bounds__(THREADS)
void k_pass1(const float4* __restrict__ lg, const float4* __restrict__ tg,
             ushort4* __restrict__ ws16, unsigned* __restrict__ hist1) {
    __shared__ unsigned h[BINS1];
    int t = threadIdx.x;
    for (int i = t; i < BINS1; i += THREADS) h[i] = 0;
    __syncthreads();

    int row = blockIdx.x >> 5;
    int chunk = blockIdx.x & 31;
    int base = row * ROW_N4 + chunk * CHUNK4;

#pragma unroll
    for (int j = 0; j < 8; ++j) {
        int idx = base + j * THREADS + t;
        float4 x = lg[idx];
        float4 y = tg[idx];
        unsigned u0 = to_u16(loss_fast(x.x, y.x));
        unsigned u1 = to_u16(loss_fast(x.y, y.y));
        unsigned u2 = to_u16(loss_fast(x.z, y.z));
        unsigned u3 = to_u16(loss_fast(x.w, y.w));
        atomicAdd(&h[u0 >> 5], 1u);
        atomicAdd(&h[u1 >> 5], 1u);
        atomicAdd(&h[u2 >> 5], 1u);
        atomicAdd(&h[u3 >> 5], 1u);
        if (STORE) ws16[idx] = make_ushort4((unsigned short)u0, (unsigned short)u1,
                                            (unsigned short)u2, (unsigned short)u3);
    }
    __syncthreads();
    unsigned* gh = hist1 + row * BINS1;
    for (int i = t; i < BINS1; i += THREADS) {
        unsigned c = h[i];
        if (c) atomicAdd(&gh[i], c);
    }
}

// ---------- Scan 1: per-row candidate bin b1, rem1 ----------
__global__ __launch_bounds__(THREADS)
void k_scan1(const unsigned* __restrict__ hist1, uint2* __restrict__ state1) {
    int row = blockIdx.x;
    int t = threadIdx.x;
    __shared__ unsigned h[BINS1];
    __shared__ unsigned csum[THREADS];
    for (int i = t; i < BINS1; i += THREADS) h[i] = hist1[row * BINS1 + i];
    __syncthreads();

    unsigned s = 0;
#pragma unroll
    for (int j = 0; j < 8; ++j) s += h[t * 8 + j];
    csum[t] = s;
    __syncthreads();
    for (int off = 1; off < THREADS; off <<= 1) {
        unsigned add = (t + off < THREADS) ? csum[t + off] : 0;
        __syncthreads();
        csum[t] += add;
        __syncthreads();
    }
    unsigned suffIncl = csum[t];
    unsigned suffExcl = (t + 1 < THREADS) ? csum[t + 1] : 0;
    if (suffExcl < K_SEL && suffIncl >= K_SEL) {
        unsigned cum = suffExcl;
        for (int j = 7; j >= 0; --j) {
            unsigned c = h[t * 8 + j];
            if (cum + c >= K_SEL) {
                state1[row] = make_uint2((unsigned)(t * 8 + j), K_SEL - cum);
                break;
            }
            cum += c;
        }
    }
}

// ---------- Pass 2: sum above b1, 32-bin sub-histogram within b1 ----------
template<bool LOAD>
__global__ __launch_bounds__(THREADS)
void k_pass2(const float4* __restrict__ lg, const float4* __restrict__ tg,
             const ushort4* __restrict__ ws16, const uint2* __restrict__ state1,
             unsigned* __restrict__ hist2c, float* __restrict__ hist2s,
             double* __restrict__ rowsum) {
    __shared__ unsigned hc[BINS2];
    __shared__ float hs[BINS2];
    __shared__ float red[THREADS];
    int t = threadIdx.x;
    if (t < BINS2) { hc[t] = 0; hs[t] = 0.0f; }
    __syncthreads();

    int row = blockIdx.x >> 5;
    int chunk = blockIdx.x & 31;
    unsigned b1 = state1[row].x;
    int base = row * ROW_N4 + chunk * CHUNK4;

    float localsum = 0.0f;
#pragma unroll
    for (int j = 0; j < 8; ++j) {
        int idx = base + j * THREADS + t;
        unsigned u0, u1, u2, u3;
        if (LOAD) {
            ushort4 w = ws16[idx];
            u0 = w.x; u1 = w.y; u2 = w.z; u3 = w.w;
        } else {
            float4 x = lg[idx];
            float4 y = tg[idx];
            u0 = to_u16(loss_fast(x.x, y.x));
            u1 = to_u16(loss_fast(x.y, y.y));
            u2 = to_u16(loss_fast(x.z, y.z));
            u3 = to_u16(loss_fast(x.w, y.w));
        }
#define PROC(U)                                                     \
        {                                                           \
            unsigned b = (U) >> 5;                                  \
            if (b > b1) localsum += u16_val(U);                     \
            else if (b == b1) {                                     \
                atomicAdd(&hc[(U) & 31u], 1u);                      \
                atomicAdd(&hs[(U) & 31u], u16_val(U));              \
            }                                                       \
        }
        PROC(u0) PROC(u1) PROC(u2) PROC(u3)
#undef PROC
    }
    __syncthreads();
    if (t < BINS2) {
        unsigned c = hc[t];
        if (c) {
            atomicAdd(&hist2c[row * BINS2 + t], c);
            atomicAdd(&hist2s[row * BINS2 + t], hs[t]);
        }
    }
    red[t] = localsum;
    __syncthreads();
    for (int off = THREADS / 2; off > 0; off >>= 1) {
        if (t < off) red[t] += red[t + off];
        __syncthreads();
    }
    if (t == 0) atomicAdd(&rowsum[row], (double)red[0]);
}

// ---------- Finalize: per-row b2 selection + global mean (1 block, 64 threads) ----------
__global__ __launch_bounds__(64)
void k_finalize(const unsigned* __restrict__ hist2c, const float* __restrict__ hist2s,
                const uint2* __restrict__ state1, const double* __restrict__ rowsum,
                float* __restrict__ out) {
    __shared__ double tot[ROWS];
    int r = threadIdx.x;
    unsigned b1 = state1[r].x;
    unsigned rem1 = state1[r].y;

    unsigned cum = 0, take = 0;
    int b2 = 0;
    for (int s = BINS2 - 1; s >= 0; --s) {
        unsigned c = hist2c[r * BINS2 + s];
        if (cum + c >= rem1) { b2 = s; take = rem1 - cum; break; }
        cum += c;
    }
    double sumhs = 0.0;
    for (int s = b2 + 1; s < BINS2; ++s) sumhs += (double)hist2s[r * BINS2 + s];
    float v = u16_val((b1 << 5) | (unsigned)b2);
    tot[r] = rowsum[r] + sumhs + (double)take * (double)v;
    __syncthreads();
    if (r == 0) {
        double s = 0.0;
        for (int i = 0; i < ROWS; ++i) s += tot[i];
        out[0] = (float)(s / ((double)ROWS * (double)K_SEL));
    }
}

extern "C" void kernel_launch(void* const* d_in, const int* in_sizes, int n_in,
                              void* d_out, int out_size, void* d_ws, size_t ws_size,
                              hipStream_t stream) {
    const float4* lg = (const float4*)d_in[0];
    const float4* tg = (const float4*)d_in[1];
    float* out = (float*)d_out;
    (void)in_sizes; (void)n_in; (void)out_size;

    // workspace layout
    char* ws = (char*)d_ws;
    unsigned* hist1  = (unsigned*)(ws);                  // 64*2048*4 = 524288
    unsigned* hist2c = (unsigned*)(ws + 524288);         // 64*32*4   = 8192
    float*    hist2s = (float*)   (ws + 532480);         // 8192
    double*   rowsum = (double*)  (ws + 540672);         // 512
    uint2*    state1 = (uint2*)   (ws + 541184);         // 512
    size_t small_bytes = 541696;
    ushort4*  ws16   = (ushort4*)(ws + 589824);          // 64*262144*2 = 33554432
    size_t needed_store = 589824 + 33554432;

    bool store = (ws_size >= needed_store);

    (void)hipMemsetAsync(d_ws, 0, small_bytes, stream);

    dim3 big(ROWS * 32);   // 2048 blocks
    if (store) {
        k_pass1<true><<<big, THREADS, 0, stream>>>(lg, tg, ws16, hist1);
        k_scan1<<<ROWS, THREADS, 0, stream>>>(hist1, state1);
        k_pass2<true><<<big, THREADS, 0, stream>>>(lg, tg, ws16, state1, hist2c, hist2s, rowsum);
    } else {
        k_pass1<false><<<big, THREADS, 0, stream>>>(lg, tg, ws16, hist1);
        k_scan1<<<ROWS, THREADS, 0, stream>>>(hist1, state1);
        k_pass2<false><<<big, THREADS, 0, stream>>>(lg, tg, ws16, state1, hist2c, hist2s, rowsum);
    }
    k_finalize<<<1, 64, 0, stream>>>(hist2c, hist2s, state1, rowsum, out);
}

// Round 4
// 61.182 us; speedup vs baseline: 2.1169x; 1.0194x over previous
//
#include <hip/hip_runtime.h>

// B=16, C=4, H=512, W=512 ; rows=64 ; row length=262144 ; k=26214
// answer = sum(topk loss per row) / (64*26214)

#define ROWS 64
#define ROW_N4 65536            // float4 per row
#define K_SEL 26214u
#define CHUNK4 2048             // float4 per block
#define THREADS 256
#define BINS1 2048              // top-11 bits of u16
#define BINS2 32                // low-5 bits of u16
#define NSUB 4                  // interleaved sub-histogram copies (contention /4)

// fast BCE-with-logits: max(x,0) - x*y + log1p(exp(-|x|))
// log1p(e^-a) = ln2 * log2(1 + 2^(-a*log2e)) -> v_exp_f32 + v_log_f32
__device__ __forceinline__ float loss_fast(float x, float y) {
    float a = fabsf(x);
    float t = __builtin_amdgcn_exp2f(a * -1.44269504088896f);       // e^-a
    float sp = 0.69314718055995f * __builtin_amdgcn_logf(1.0f + t); // ln2*log2(1+t)
    return fmaxf(x, 0.0f) - x * y + sp;
}
// round float bits to nearest 16-bit prefix (monotone, unbiased)
__device__ __forceinline__ unsigned to_u16(float l) {
    return (__float_as_uint(l) + 0x8000u) >> 16;
}
__device__ __forceinline__ float u16_val(unsigned u) {
    return __uint_as_float(u << 16);
}

// ---------- Pass 1: loss -> 2048-bin histogram (4 interleaved sub-copies) ----------
__global__ __launch_bounds__(THREADS)
void k_pass1(const float4* __restrict__ lg, const float4* __restrict__ tg,
             unsigned* __restrict__ hist1) {
    __shared__ unsigned h[BINS1 * NSUB];          // 32 KB
    int t = threadIdx.x;
    for (int i = t; i < BINS1 * NSUB; i += THREADS) h[i] = 0;
    __syncthreads();

    int row = blockIdx.x >> 5;
    int chunk = blockIdx.x & 31;
    int base = row * ROW_N4 + chunk * CHUNK4;
    int sub = t & (NSUB - 1);

#pragma unroll
    for (int j = 0; j < 8; ++j) {
        int idx = base + j * THREADS + t;
        float4 x = lg[idx];
        float4 y = tg[idx];
        unsigned u0 = to_u16(loss_fast(x.x, y.x));
        unsigned u1 = to_u16(loss_fast(x.y, y.y));
        unsigned u2 = to_u16(loss_fast(x.z, y.z));
        unsigned u3 = to_u16(loss_fast(x.w, y.w));
        atomicAdd(&h[(u0 >> 5) * NSUB + sub], 1u);
        atomicAdd(&h[(u1 >> 5) * NSUB + sub], 1u);
        atomicAdd(&h[(u2 >> 5) * NSUB + sub], 1u);
        atomicAdd(&h[(u3 >> 5) * NSUB + sub], 1u);
    }
    __syncthreads();
    unsigned* gh = hist1 + row * BINS1;
    const uint4* h4 = (const uint4*)h;
    for (int i = t; i < BINS1; i += THREADS) {
        uint4 v = h4[i];
        unsigned c = v.x + v.y + v.z + v.w;
        if (c) atomicAdd(&gh[i], c);
    }
}

// ---------- Scan 1: per-row candidate bin b1, rem1 ----------
__global__ __launch_bounds__(THREADS)
void k_scan1(const unsigned* __restrict__ hist1, uint2* __restrict__ state1) {
    int row = blockIdx.x;
    int t = threadIdx.x;
    __shared__ unsigned h[BINS1];
    __shared__ unsigned csum[THREADS];
    for (int i = t; i < BINS1; i += THREADS) h[i] = hist1[row * BINS1 + i];
    __syncthreads();

    unsigned s = 0;
#pragma unroll
    for (int j = 0; j < 8; ++j) s += h[t * 8 + j];
    csum[t] = s;
    __syncthreads();
    for (int off = 1; off < THREADS; off <<= 1) {
        unsigned add = (t + off < THREADS) ? csum[t + off] : 0;
        __syncthreads();
        csum[t] += add;
        __syncthreads();
    }
    unsigned suffIncl = csum[t];
    unsigned suffExcl = (t + 1 < THREADS) ? csum[t + 1] : 0;
    if (suffExcl < K_SEL && suffIncl >= K_SEL) {
        unsigned cum = suffExcl;
        for (int j = 7; j >= 0; --j) {
            unsigned c = h[t * 8 + j];
            if (cum + c >= K_SEL) {
                state1[row] = make_uint2((unsigned)(t * 8 + j), K_SEL - cum);
                break;
            }
            cum += c;
        }
    }
}

// ---------- Pass 2: recompute loss; sum above b1; 32-bin sub-hist within b1 ----------
__global__ __launch_bounds__(THREADS)
void k_pass2(const float4* __restrict__ lg, const float4* __restrict__ tg,
             const uint2* __restrict__ state1,
             unsigned* __restrict__ hist2c, float* __restrict__ hist2s,
             double* __restrict__ rowsum) {
    __shared__ unsigned hc[BINS2 * NSUB];
    __shared__ float hs[BINS2 * NSUB];
    __shared__ float red[THREADS];
    int t = threadIdx.x;
    if (t < BINS2 * NSUB) { hc[t] = 0; hs[t] = 0.0f; }
    __syncthreads();

    int row = blockIdx.x >> 5;
    int chunk = blockIdx.x & 31;
    unsigned b1 = state1[row].x;
    int base = row * ROW_N4 + chunk * CHUNK4;
    int sub = t & (NSUB - 1);

    float localsum = 0.0f;
#pragma unroll
    for (int j = 0; j < 8; ++j) {
        int idx = base + j * THREADS + t;
        float4 x = lg[idx];
        float4 y = tg[idx];
        unsigned u0 = to_u16(loss_fast(x.x, y.x));
        unsigned u1 = to_u16(loss_fast(x.y, y.y));
        unsigned u2 = to_u16(loss_fast(x.z, y.z));
        unsigned u3 = to_u16(loss_fast(x.w, y.w));
#define PROC(U)                                                     \
        {                                                           \
            unsigned b = (U) >> 5;                                  \
            if (b > b1) localsum += u16_val(U);                     \
            else if (b == b1) {                                     \
                atomicAdd(&hc[((U) & 31u) * NSUB + sub], 1u);       \
                atomicAdd(&hs[((U) & 31u) * NSUB + sub], u16_val(U)); \
            }                                                       \
        }
        PROC(u0) PROC(u1) PROC(u2) PROC(u3)
#undef PROC
    }
    __syncthreads();
    if (t < BINS2) {
        unsigned c = hc[t * NSUB] + hc[t * NSUB + 1] + hc[t * NSUB + 2] + hc[t * NSUB + 3];
        float sflt = hs[t * NSUB] + hs[t * NSUB + 1] + hs[t * NSUB + 2] + hs[t * NSUB + 3];
        if (c) {
            atomicAdd(&hist2c[row * BINS2 + t], c);
            atomicAdd(&hist2s[row * BINS2 + t], sflt);
        }
    }
    red[t] = localsum;
    __syncthreads();
    for (int off = THREADS / 2; off > 0; off >>= 1) {
        if (t < off) red[t] += red[t + off];
        __syncthreads();
    }
    if (t == 0) atomicAdd(&rowsum[row], (double)red[0]);
}

// ---------- Finalize: per-row b2 selection + global mean (1 block, 64 threads) ----------
__global__ __launch_bounds__(64)
void k_finalize(const unsigned* __restrict__ hist2c, const float* __restrict__ hist2s,
                const uint2* __restrict__ state1, const double* __restrict__ rowsum,
                float* __restrict__ out) {
    __shared__ double tot[ROWS];
    int r = threadIdx.x;
    unsigned b1 = state1[r].x;
    unsigned rem1 = state1[r].y;

    unsigned cum = 0, take = 0;
    int b2 = 0;
    for (int s = BINS2 - 1; s >= 0; --s) {
        unsigned c = hist2c[r * BINS2 + s];
        if (cum + c >= rem1) { b2 = s; take = rem1 - cum; break; }
        cum += c;
    }
    double sumhs = 0.0;
    for (int s = b2 + 1; s < BINS2; ++s) sumhs += (double)hist2s[r * BINS2 + s];
    float v = u16_val((b1 << 5) | (unsigned)b2);
    tot[r] = rowsum[r] + sumhs + (double)take * (double)v;
    __syncthreads();
    if (r == 0) {
        double s = 0.0;
        for (int i = 0; i < ROWS; ++i) s += tot[i];
        out[0] = (float)(s / ((double)ROWS * (double)K_SEL));
    }
}

extern "C" void kernel_launch(void* const* d_in, const int* in_sizes, int n_in,
                              void* d_out, int out_size, void* d_ws, size_t ws_size,
                              hipStream_t stream) {
    const float4* lg = (const float4*)d_in[0];
    const float4* tg = (const float4*)d_in[1];
    float* out = (float*)d_out;
    (void)in_sizes; (void)n_in; (void)out_size; (void)ws_size;

    // workspace layout
    char* ws = (char*)d_ws;
    unsigned* hist1  = (unsigned*)(ws);                  // 64*2048*4 = 524288
    unsigned* hist2c = (unsigned*)(ws + 524288);         // 64*32*4   = 8192
    float*    hist2s = (float*)   (ws + 532480);         // 8192
    double*   rowsum = (double*)  (ws + 540672);         // 512
    uint2*    state1 = (uint2*)   (ws + 541184);         // 512
    size_t small_bytes = 541696;

    (void)hipMemsetAsync(d_ws, 0, small_bytes, stream);

    dim3 big(ROWS * 32);   // 2048 blocks
    k_pass1<<<big, THREADS, 0, stream>>>(lg, tg, hist1);
    k_scan1<<<ROWS, THREADS, 0, stream>>>(hist1, state1);
    k_pass2<<<big, THREADS, 0, stream>>>(lg, tg, state1, hist2c, hist2s, rowsum);
    k_finalize<<<1, 64, 0, stream>>>(hist2c, hist2s, state1, rowsum, out);
}